// Round 15
// baseline (268.124 us; speedup 1.0000x reference)
//
#include <hip/hip_runtime.h>
#include <math.h>

// Problem constants
#define NPOS   65536        // 16*64*64 positions
#define NE     1024         // codebook size
#define HW     4096         // 64*64
#define BETA   0.25

// Output layout (floats) in d_out, reference return order:
// loss(1), z_q_st(16*64*64*64), perplexity(1), min_encodings(65536*1024), indices(65536)
#define OUT_LOSS 0LL
#define OUT_ZQ   1LL
#define OUT_PERP 4194305LL
#define OUT_ENC  4194306LL
#define OUT_IDX  71303170LL

// numpy pairwise_sum for n=64 (8 accumulators, stride 8, tree combine) of squares.
__device__ __forceinline__ float pairwise_sum_sq64(const float v[64]) {
#pragma clang fp contract(off)
    float r[8];
#pragma unroll
    for (int k = 0; k < 8; ++k) r[k] = v[k] * v[k];
#pragma unroll
    for (int i = 8; i < 64; i += 8) {
#pragma unroll
        for (int k = 0; k < 8; ++k) {
            float s = v[i + k] * v[i + k];
            r[k] = r[k] + s;
        }
    }
    return ((r[0] + r[1]) + (r[2] + r[3])) + ((r[4] + r[5]) + (r[6] + r[7]));
}

// K0: codebook norms + transposed codebook + zero counts + zero loss accumulator
__global__ void vq_prep(const float* __restrict__ emb, float* __restrict__ enorm,
                        float* __restrict__ embT, int* __restrict__ counts,
                        double* __restrict__ lacc) {
    int t = blockIdx.x * 256 + threadIdx.x;   // 0..1023
    if (t < NE) {
        float v[64];
#pragma unroll
        for (int c = 0; c < 64; ++c) v[c] = emb[t * 64 + c];
        enorm[t] = pairwise_sum_sq64(v);
#pragma unroll
        for (int c = 0; c < 64; ++c) embT[c * NE + t] = v[c];  // coalesced
        counts[t] = 0;
    }
    if (t == 0) *lacc = 0.0;
}

// K1: main. grid = 4096 blocks x 256 threads (4 waves), target 4 blocks/CU.
// NEW GEOMETRY (fixes the 14-round LDS:VALU:latency deadlock):
//   block = 16 positions x 1024 codes; wave (wp,wc) = 8 pos x 512 codes;
//   lane owns 8 consecutive codes (wc*512 + lane*8 .. +7).
//   z[c][wave's 8 pos] is WAVE-UNIFORM -> scalar-pipe loads (readfirstlane'd
//   base, unrolled offsets -> s_load_dwordx8), zero LDS/VGPR pressure.
//   Only e comes from LDS: 2 ds_read_b128 per 64 FMAs (2x better ratio than
//   all prior rounds). e double-buffered in 4-c chunks (16 KB/buf) -> LDS
//   ~37 KB -> 4 blocks/CU = 4 waves/SIMD latency cover.
// Bit-exactness: dot = single accumulator, sequential c fmaf chain (chunks
// ascending, acc carried); szn numpy-pairwise; dist (szn+enorm)-2*acc;
// argmin ascending j strict < + lex reduces. Identical to verified R9-R14.
__global__ __launch_bounds__(256, 4)
void vq_main(const float* __restrict__ z, const float* __restrict__ emb,
             const float* __restrict__ embT, const float* __restrict__ enorm,
             int* __restrict__ counts, double* __restrict__ lacc,
             float* __restrict__ out) {
    __shared__ float e_lds[2][4 * NE];      // 2 x 16 KB
    __shared__ float en_lds[NE];            // 4 KB
    __shared__ float szn_lds[16];
    __shared__ float cand_d[2][16];
    __shared__ int   cand_j[2][16];
    __shared__ int   runj[16];

    const int tid  = threadIdx.x;
    const int lane = tid & 63;
    const int w    = tid >> 6;
    const int wp   = w >> 1;          // 0/1: position octet
    const int wc   = w & 1;           // 0/1: code half
    const int n0   = blockIdx.x * 16;
    const int b    = n0 >> 12;
    const int hw0  = n0 & 4095;
    const int zbase = b * (64 * HW) + hw0;
    const int ebase = wc * 512 + lane * 8;   // this lane's 8 codes (in-tile)

    // ---- stage enorm ----
#pragma unroll
    for (int it = 0; it < 4; ++it) en_lds[it * 256 + tid] = enorm[it * 256 + tid];

    // ---- szn for the block's 16 positions (verified numpy pairwise order) ----
    if (tid < 16) {
#pragma clang fp contract(off)
        float r[8];
#pragma unroll
        for (int k = 0; k < 8; ++k) { float x = z[zbase + k * HW + tid]; r[k] = x * x; }
#pragma unroll
        for (int i = 8; i < 64; i += 8) {
#pragma unroll
            for (int k = 0; k < 8; ++k) {
                float x = z[zbase + (i + k) * HW + tid];
                float s = x * x;
                r[k] = r[k] + s;
            }
        }
        szn_lds[tid] = ((r[0] + r[1]) + (r[2] + r[3])) + ((r[4] + r[5]) + (r[6] + r[7]));
    }

    // ---- prologue: stage e chunk 0 (c = 0..3) into buf 0 ----
#pragma unroll
    for (int it = 0; it < 4; ++it) {
        const int idx4 = it * 256 + tid;          // 0..1023
        const int cc   = idx4 >> 8;               // 0..3
        const int q4   = idx4 & 255;              // 0..255
        const float4 v = *(const float4*)(embT + cc * NE + q4 * 4);
        *(float4*)(&e_lds[0][cc * NE + q4 * 4]) = v;
    }
    __syncthreads();

    // wave-uniform z row base (8 consecutive positions per wave)
    const int zoffu = __builtin_amdgcn_readfirstlane(zbase + wp * 8);
    const float* __restrict__ zw = z + zoffu;

    float acc[8][8];
#pragma unroll
    for (int p = 0; p < 8; ++p)
#pragma unroll
        for (int u = 0; u < 8; ++u) acc[p][u] = 0.0f;

    // ---- k-loop: 16 chunks of 4 c, double-buffered e ----
#define VQ_BODY(CUR, NXT, CH)                                                   \
    do {                                                                        \
        if ((CH) + 1 < 16) {                                                    \
            const int c0n = ((CH) + 1) * 4;                                     \
            _Pragma("unroll")                                                   \
            for (int it = 0; it < 4; ++it) {                                    \
                const int idx4 = it * 256 + tid;                                \
                const int cc   = idx4 >> 8;                                     \
                const int q4   = idx4 & 255;                                    \
                const float4 v = *(const float4*)(embT + (c0n + cc) * NE + q4 * 4); \
                *(float4*)(&e_lds[NXT][cc * NE + q4 * 4]) = v;                  \
            }                                                                   \
        }                                                                       \
        {                                                                       \
            const float* __restrict__ zwc = zw + (CH) * 4 * HW;                 \
            float zc[4][8];                                                     \
            _Pragma("unroll")                                                   \
            for (int cc = 0; cc < 4; ++cc)                                      \
                _Pragma("unroll")                                               \
                for (int p = 0; p < 8; ++p) zc[cc][p] = zwc[cc * HW + p];       \
            _Pragma("unroll")                                                   \
            for (int cc = 0; cc < 4; ++cc) {                                    \
                const float4 ea = *(const float4*)(&e_lds[CUR][cc * NE + ebase]);     \
                const float4 eb = *(const float4*)(&e_lds[CUR][cc * NE + ebase + 4]); \
                const float ef[8] = {ea.x, ea.y, ea.z, ea.w, eb.x, eb.y, eb.z, eb.w}; \
                _Pragma("unroll")                                               \
                for (int p = 0; p < 8; ++p)                                     \
                    _Pragma("unroll")                                           \
                    for (int u = 0; u < 8; ++u)                                 \
                        acc[p][u] = fmaf(zc[cc][p], ef[u], acc[p][u]);          \
            }                                                                   \
        }                                                                       \
        __syncthreads();                                                        \
    } while (0)

    for (int ch = 0; ch < 16; ch += 2) {
        VQ_BODY(0, 1, ch);
        VQ_BODY(1, 0, ch + 1);
    }
#undef VQ_BODY

    // ---- distances + argmin (lane scans its 8 codes ascending, strict <) ----
#pragma unroll
    for (int p = 0; p < 8; ++p) {
        const float sz = szn_lds[wp * 8 + p];
        float bd = 3.4e38f;
        int   bj = 0;
#pragma unroll
        for (int u = 0; u < 8; ++u) {
            const int j = ebase + u;              // ascending within thread
            const float dj = (sz + en_lds[j]) - 2.0f * acc[p][u];
            if (dj < bd) { bd = dj; bj = j; }
        }
        // full-wave lex reduce (64 lanes cover 512 ascending codes)
#pragma unroll
        for (int m = 1; m < 64; m <<= 1) {
            const float od = __shfl_xor(bd, m, 64);
            const int   oj = __shfl_xor(bj, m, 64);
            if (od < bd || (od == bd && oj < bj)) { bd = od; bj = oj; }
        }
        if (lane == 0) { cand_d[wc][wp * 8 + p] = bd; cand_j[wc][wp * 8 + p] = bj; }
    }
    __syncthreads();

    // merge the two code-halves (wc=0 codes < wc=1 codes: strict < = first-min)
    if (tid < 16) {
        const float d0 = cand_d[0][tid];
        const float d1 = cand_d[1][tid];
        const int   jf = (d1 < d0) ? cand_j[1][tid] : cand_j[0][tid];
        runj[tid] = jf;
        atomicAdd(&counts[jf], 1);
        out[OUT_IDX + n0 + tid] = (float)jf;       // idx as f32
    }
    __syncthreads();

    // ---- z_q_st = z + (z_q - z) + loss partials ----
    // thread: pos = tid&15, channels (tid>>4)*4 .. +3 (fresh z loads = input bits)
    {
        const int pos  = tid & 15;
        const int cseg = tid >> 4;                // 0..15
        const int myj  = runj[pos];
        double acc2 = 0.0;
#pragma unroll
        for (int k = 0; k < 4; ++k) {
            const int c = cseg * 4 + k;
            const float zc = z[zbase + c * HW + pos];
            const float ec = emb[myj * 64 + c];
            const float t  = __fsub_rn(ec, zc);   // z_q - z
            const float o  = __fadd_rn(zc, t);    // z + (z_q - z)
            out[OUT_ZQ + (long long)b * (64LL * HW) + (long long)c * HW + hw0 + pos] = o;
            const float s = __fmul_rn(t, t);      // (z_q - z)^2 rounded f32
            acc2 += (double)s;
        }
#pragma unroll
        for (int off = 32; off > 0; off >>= 1) acc2 += __shfl_down(acc2, off);
        if (lane == 0) atomicAdd(lacc, acc2);
    }

    // ---- one-hot: 16 rows x 512 ull, value computed inline (no scatter pass) ----
    {
        unsigned long long* __restrict__ enc8 =
            (unsigned long long*)(out + OUT_ENC);
        const long long encb = (long long)n0 * 512;
#pragma unroll
        for (int i = 0; i < 32; ++i) {
            const int g   = i * 256 + tid;        // 0..8191
            const int row = g >> 9;               // 0..15
            const int col = g & 511;
            const int jr  = runj[row];
            const int c0  = col * 2;
            unsigned long long v = 0ULL;
            if (c0 == jr)     v = 0x3f800000ULL;
            if (c0 + 1 == jr) v = 0x3f800000ULL << 32;
            __builtin_nontemporal_store(v, &enc8[encb + (long long)row * 512 + col]);
        }
    }
}

// K2: perplexity + loss finalize. 1 block x 1024 threads.
__global__ void vq_finalize(const int* __restrict__ counts,
                            const double* __restrict__ lacc,
                            float* __restrict__ out) {
    __shared__ float red[1024];
    const int t = threadIdx.x;
    const float p = (float)counts[t] * (1.0f / 65536.0f); // exact (count int, /2^16)
    const float term = p * logf(p + 1e-10f);
    red[t] = term;
    __syncthreads();
    for (int s = 512; s > 0; s >>= 1) {
        if (t < s) red[t] += red[t + s];
        __syncthreads();
    }
    if (t == 0) {
        out[OUT_PERP] = expf(-red[0]);
        out[OUT_LOSS] = (float)(BETA * (*lacc / 4194304.0));
    }
}

extern "C" void kernel_launch(void* const* d_in, const int* in_sizes, int n_in,
                              void* d_out, int out_size, void* d_ws, size_t ws_size,
                              hipStream_t stream) {
    const float* z   = (const float*)d_in[0];   // (16,64,64,64) f32
    const float* emb = (const float*)d_in[1];   // (1024,64) f32
    float* out = (float*)d_out;

    double* lacc  = (double*)d_ws;
    int*    cnts  = (int*)((char*)d_ws + 16);
    float*  enorm = (float*)((char*)d_ws + 16 + NE * sizeof(int));
    float*  embT  = (float*)((char*)d_ws + 16 + NE * sizeof(int) + NE * sizeof(float));

    vq_prep<<<4, 256, 0, stream>>>(emb, enorm, embT, cnts, lacc);
    vq_main<<<4096, 256, 0, stream>>>(z, emb, embT, enorm, cnts, lacc, out);
    vq_finalize<<<1, 1024, 0, stream>>>(cnts, lacc, out);
}